// Round 1
// baseline (234.025 us; speedup 1.0000x reference)
//
#include <hip/hip_runtime.h>
#include <stdint.h>

// Problem constants (match reference)
constexpr int B_       = 2048;
constexpr int N_       = 50000;
constexpr int KOUT     = 101;    // NUM_HARD_NEGATIVES + 1
constexpr int NBINS    = 4096;   // top-12-bit histogram of sortable key
constexpr int CAND_CAP = 2048;
constexpr int NTHREADS = 256;

// Order-preserving float -> uint32 map (larger float => larger key)
__device__ __forceinline__ unsigned sortkey(float f) {
    unsigned u = __float_as_uint(f);
    return (u & 0x80000000u) ? ~u : (u | 0x80000000u);
}
__device__ __forceinline__ float unsortkey(unsigned k) {
    unsigned u = (k & 0x80000000u) ? (k & 0x7FFFFFFFu) : ~k;
    return __uint_as_float(u);
}

__global__ __launch_bounds__(NTHREADS) void hnm_topk(
        const float* __restrict__ logits,
        const float* __restrict__ labels,
        float* __restrict__ out_logits,
        float* __restrict__ out_labels) {
    __shared__ unsigned           s_hist[NBINS];
    __shared__ unsigned long long s_cand[CAND_CAP];
    __shared__ int                s_part[NTHREADS];
    __shared__ int                s_p;
    __shared__ float              s_pval;
    __shared__ int                s_ncand;
    __shared__ int                s_T;

    const int row = blockIdx.x;
    const int tid = threadIdx.x;
    const float*  lrow  = logits + (size_t)row * N_;
    const float*  brow  = labels + (size_t)row * N_;
    const float4* lrow4 = (const float4*)lrow;
    const float4* brow4 = (const float4*)brow;

    for (int i = tid; i < NBINS; i += NTHREADS) s_hist[i] = 0u;
    if (tid == 0) { s_p = -1; s_ncand = 0; }
    __syncthreads();

    // ---- Pass 1: histogram of keys + find positive index ----
    // N_ = 50000 -> exactly 12500 float4, no tail.
    for (int i = tid; i < N_ / 4; i += NTHREADS) {
        float4 v  = lrow4[i];
        float4 lb = brow4[i];
        atomicAdd(&s_hist[sortkey(v.x) >> 20], 1u);
        atomicAdd(&s_hist[sortkey(v.y) >> 20], 1u);
        atomicAdd(&s_hist[sortkey(v.z) >> 20], 1u);
        atomicAdd(&s_hist[sortkey(v.w) >> 20], 1u);
        if (lb.x != 0.0f) s_p = 4 * i + 0;
        if (lb.y != 0.0f) s_p = 4 * i + 1;
        if (lb.z != 0.0f) s_p = 4 * i + 2;
        if (lb.w != 0.0f) s_p = 4 * i + 3;
    }
    __syncthreads();

    // Remove the positive from the histogram (it is output slot 0, not a negative)
    if (tid == 0) {
        float pv = lrow[s_p];
        s_pval = pv;
        s_hist[sortkey(pv) >> 20] -= 1u;
    }
    __syncthreads();

    // ---- Find threshold bin T: smallest b with count(bins >= b) >= 100 ----
    {
        constexpr int SEG = NBINS / NTHREADS;  // 16 bins per thread
        int base = tid * SEG;
        int lsum = 0;
        #pragma unroll
        for (int j = 0; j < SEG; ++j) lsum += (int)s_hist[base + j];
        s_part[tid] = lsum;
        __syncthreads();
        if (tid == 0) {
            int acc = 0;
            int seg = NTHREADS - 1;
            for (; seg >= 0; --seg) {
                if (acc + s_part[seg] >= KOUT - 1) break;
                acc += s_part[seg];
            }
            int b = (seg + 1) * SEG - 1;
            for (; b >= seg * SEG; --b) {
                acc += (int)s_hist[b];
                if (acc >= KOUT - 1) break;
            }
            s_T = b;
        }
    }
    __syncthreads();

    // ---- Pass 2: collect candidates (bin >= T, excluding positive) ----
    const int T = s_T;
    const int p = s_p;
    for (int i = tid; i < N_ / 4; i += NTHREADS) {
        float4 v = lrow4[i];
        float vv[4] = {v.x, v.y, v.z, v.w};
        int i4 = 4 * i;
        #pragma unroll
        for (int c = 0; c < 4; ++c) {
            unsigned k = sortkey(vv[c]);
            int idx = i4 + c;
            if ((int)(k >> 20) >= T && idx != p) {
                int pos = atomicAdd(&s_ncand, 1);
                if (pos < CAND_CAP) {
                    // high 32: sortable key (descending); low 32: ~idx so that
                    // equal values order lower-index-first under descending sort
                    s_cand[pos] = ((unsigned long long)k << 32) |
                                  (unsigned long long)(unsigned)(~(unsigned)idx);
                }
            }
        }
    }
    __syncthreads();

    int nc = s_ncand;
    if (nc > CAND_CAP) nc = CAND_CAP;
    int P = 2;
    while (P < nc) P <<= 1;
    for (int i = nc + tid; i < P; i += NTHREADS) s_cand[i] = 0ULL;  // -inf sentinel
    __syncthreads();

    // ---- Bitonic sort descending over P elements ----
    for (int ksz = 2; ksz <= P; ksz <<= 1) {
        for (int j = ksz >> 1; j > 0; j >>= 1) {
            for (int i = tid; i < P; i += NTHREADS) {
                int ixj = i ^ j;
                if (ixj > i) {
                    unsigned long long a = s_cand[i];
                    unsigned long long b = s_cand[ixj];
                    bool swap_ = ((i & ksz) == 0) ? (a < b) : (a > b);
                    if (swap_) { s_cand[i] = b; s_cand[ixj] = a; }
                }
            }
            __syncthreads();
        }
    }

    // ---- Emit ----
    float* og = out_logits + (size_t)row * KOUT;
    float* ol = out_labels + (size_t)row * KOUT;
    if (tid == 0) { og[0] = s_pval; ol[0] = 1.0f; }
    if (tid >= 1 && tid < KOUT) {
        unsigned long long pk = s_cand[tid - 1];
        og[tid] = unsortkey((unsigned)(pk >> 32));
        ol[tid] = 0.0f;
    }
}

extern "C" void kernel_launch(void* const* d_in, const int* in_sizes, int n_in,
                              void* d_out, int out_size, void* d_ws, size_t ws_size,
                              hipStream_t stream) {
    const float* logits = (const float*)d_in[0];
    const float* labels = (const float*)d_in[1];
    float* out_logits = (float*)d_out;
    float* out_labels = out_logits + (size_t)B_ * KOUT;
    hnm_topk<<<B_, NTHREADS, 0, stream>>>(logits, labels, out_logits, out_labels);
}

// Round 3
// 231.599 us; speedup vs baseline: 1.0105x; 1.0105x over previous
//
#include <hip/hip_runtime.h>
#include <stdint.h>

// Problem constants (match reference)
constexpr int B_       = 2048;
constexpr int N_       = 50000;
constexpr int KOUT     = 101;    // NUM_HARD_NEGATIVES + 1
constexpr int NBINS    = 2048;   // top-11-bit histogram of sortable key
constexpr int KEYSHIFT = 21;     // 32 - 11
constexpr int CAND_CAP = 1024;
constexpr int NTHREADS = 256;

// native vector type (works with __builtin_nontemporal_load, unlike HIP float4)
typedef float  floatx4 __attribute__((ext_vector_type(4)));

// Order-preserving float -> uint32 map (larger float => larger key)
__device__ __forceinline__ unsigned sortkey(float f) {
    unsigned u = __float_as_uint(f);
    return (u & 0x80000000u) ? ~u : (u | 0x80000000u);
}
__device__ __forceinline__ float unsortkey(unsigned k) {
    unsigned u = (k & 0x80000000u) ? (k & 0x7FFFFFFFu) : ~k;
    return __uint_as_float(u);
}

__global__ __launch_bounds__(NTHREADS) void hnm_topk(
        const float* __restrict__ logits,
        const float* __restrict__ labels,
        float* __restrict__ out_logits,
        float* __restrict__ out_labels) {
    __shared__ unsigned           s_hist[NBINS];
    __shared__ unsigned long long s_cand[CAND_CAP];
    __shared__ int                s_part[NTHREADS];
    __shared__ int                s_p;
    __shared__ float              s_pval;
    __shared__ int                s_ncand;
    __shared__ int                s_T;

    const int row = blockIdx.x;
    const int tid = threadIdx.x;
    const float*   lrow  = logits + (size_t)row * N_;
    const float*   brow  = labels + (size_t)row * N_;
    const floatx4* lrow4 = (const floatx4*)lrow;
    const floatx4* brow4 = (const floatx4*)brow;

    for (int i = tid; i < NBINS; i += NTHREADS) s_hist[i] = 0u;
    if (tid == 0) { s_p = -1; s_ncand = 0; }
    __syncthreads();

    // ---- Pass 1: histogram of keys + find positive index ----
    // N_ = 50000 -> exactly 12500 float4, no tail.
    for (int i = tid; i < N_ / 4; i += NTHREADS) {
        floatx4 v  = lrow4[i];
        // labels are read-once: non-temporal so they don't evict logits
        floatx4 lb = __builtin_nontemporal_load(&brow4[i]);
        atomicAdd(&s_hist[sortkey(v.x) >> KEYSHIFT], 1u);
        atomicAdd(&s_hist[sortkey(v.y) >> KEYSHIFT], 1u);
        atomicAdd(&s_hist[sortkey(v.z) >> KEYSHIFT], 1u);
        atomicAdd(&s_hist[sortkey(v.w) >> KEYSHIFT], 1u);
        if (lb.x != 0.0f) s_p = 4 * i + 0;
        if (lb.y != 0.0f) s_p = 4 * i + 1;
        if (lb.z != 0.0f) s_p = 4 * i + 2;
        if (lb.w != 0.0f) s_p = 4 * i + 3;
    }
    __syncthreads();

    // Remove the positive from the histogram (it is output slot 0, not a negative)
    if (tid == 0) {
        float pv = lrow[s_p];
        s_pval = pv;
        s_hist[sortkey(pv) >> KEYSHIFT] -= 1u;
    }
    __syncthreads();

    // ---- Find threshold bin T: smallest b with count(bins >= b) >= 100 ----
    {
        constexpr int SEG = NBINS / NTHREADS;  // 8 bins per thread
        int base = tid * SEG;
        int lsum = 0;
        #pragma unroll
        for (int j = 0; j < SEG; ++j) lsum += (int)s_hist[base + j];
        s_part[tid] = lsum;
        __syncthreads();
        if (tid == 0) {
            int acc = 0;
            int seg = NTHREADS - 1;
            for (; seg >= 0; --seg) {
                if (acc + s_part[seg] >= KOUT - 1) break;
                acc += s_part[seg];
            }
            int b = (seg + 1) * SEG - 1;
            for (; b >= seg * SEG; --b) {
                acc += (int)s_hist[b];
                if (acc >= KOUT - 1) break;
            }
            s_T = b;
        }
    }
    __syncthreads();

    // ---- Pass 2: collect candidates (bin >= T, excluding positive) ----
    const int T = s_T;
    const int p = s_p;
    for (int i = tid; i < N_ / 4; i += NTHREADS) {
        floatx4 v = lrow4[i];
        float vv[4] = {v.x, v.y, v.z, v.w};
        int i4 = 4 * i;
        #pragma unroll
        for (int c = 0; c < 4; ++c) {
            unsigned k = sortkey(vv[c]);
            int idx = i4 + c;
            if ((int)(k >> KEYSHIFT) >= T && idx != p) {
                int pos = atomicAdd(&s_ncand, 1);
                if (pos < CAND_CAP) {
                    // high 32: sortable key (descending); low 32: ~idx so that
                    // equal values order lower-index-first under descending sort
                    s_cand[pos] = ((unsigned long long)k << 32) |
                                  (unsigned long long)(unsigned)(~(unsigned)idx);
                }
            }
        }
    }
    __syncthreads();

    int nc = s_ncand;
    if (nc > CAND_CAP) nc = CAND_CAP;
    int P = 2;
    while (P < nc) P <<= 1;
    for (int i = nc + tid; i < P; i += NTHREADS) s_cand[i] = 0ULL;  // -inf sentinel
    __syncthreads();

    // ---- Bitonic sort descending over P elements ----
    for (int ksz = 2; ksz <= P; ksz <<= 1) {
        for (int j = ksz >> 1; j > 0; j >>= 1) {
            for (int i = tid; i < P; i += NTHREADS) {
                int ixj = i ^ j;
                if (ixj > i) {
                    unsigned long long a = s_cand[i];
                    unsigned long long b = s_cand[ixj];
                    bool swap_ = ((i & ksz) == 0) ? (a < b) : (a > b);
                    if (swap_) { s_cand[i] = b; s_cand[ixj] = a; }
                }
            }
            __syncthreads();
        }
    }

    // ---- Emit ----
    float* og = out_logits + (size_t)row * KOUT;
    float* ol = out_labels + (size_t)row * KOUT;
    if (tid == 0) { og[0] = s_pval; ol[0] = 1.0f; }
    if (tid >= 1 && tid < KOUT) {
        unsigned long long pk = s_cand[tid - 1];
        og[tid] = unsortkey((unsigned)(pk >> 32));
        ol[tid] = 0.0f;
    }
}

extern "C" void kernel_launch(void* const* d_in, const int* in_sizes, int n_in,
                              void* d_out, int out_size, void* d_ws, size_t ws_size,
                              hipStream_t stream) {
    const float* logits = (const float*)d_in[0];
    const float* labels = (const float*)d_in[1];
    float* out_logits = (float*)d_out;
    float* out_labels = out_logits + (size_t)B_ * KOUT;
    hnm_topk<<<B_, NTHREADS, 0, stream>>>(logits, labels, out_logits, out_labels);
}